// Round 2
// baseline (175.991 us; speedup 1.0000x reference)
//
#include <hip/hip_runtime.h>

#define N_NODES 100000
#define N_EDGES 1600000
#define F 16
#define EDGES_PER_BLOCK 256
#define FSLAB 260   // 16 k-cells * 16 i + 4 pad (keeps float4 16B alignment; 260 ≡ 4 mod 32 banks)

// Explicit zero kernel: hipMemsetAsync inside kernel_launch proved unreliable
// across graph capture / repeat calls (R0 post-timing accumulation). Kernel
// nodes always capture and order correctly on the stream.
__global__ __launch_bounds__(256) void zero_out_kernel(float4* __restrict__ out, int n4) {
    int i = blockIdx.x * 256 + threadIdx.x;
    if (i < n4) out[i] = make_float4(0.f, 0.f, 0.f, 0.f);
}

__global__ __launch_bounds__(256) void basis_conv_edges(
    const float* __restrict__ x,          // [N_NODES, 16]
    const int*   __restrict__ edge_index, // [2, N_EDGES]
    const float* __restrict__ edge_attr,  // [N_EDGES, 2]
    const float* __restrict__ weight,     // [4,4,16,16] row-major = [k][i][f]
    float*       __restrict__ out)        // [N_NODES, 16], zeroed by zero_out_kernel
{
    // LDS layout [f][k][i]: lane f reads 16 consecutive i-values per cell as 4x float4.
    __shared__ float wl[F * FSLAB];
    for (int idx = threadIdx.x; idx < 4096; idx += 256) {
        const int f = idx & 15;
        const int i = (idx >> 4) & 15;
        const int k = idx >> 8;
        wl[f * FSLAB + k * 16 + i] = weight[idx];
    }
    __syncthreads();

    const int f = threadIdx.x & 15;   // output feature handled by this lane
    const int s = threadIdx.x >> 4;   // edge slot within pass (0..15)
    const int ebase = blockIdx.x * EDGES_PER_BLOCK;

#pragma unroll 1
    for (int it = 0; it < EDGES_PER_BLOCK / 16; ++it) {
        const int e = ebase + it * 16 + s;

        const int row = edge_index[e];            // destination node
        const int col = edge_index[N_EDGES + e];  // source node
        const float2 attr = ((const float2*)edge_attr)[e];

        // hat basis, 4 centers on [-1,1], spacing 2/3: exactly 2 nonzero per dim
        float fu = (attr.x + 1.0f) * 1.5f;
        int iu = (int)fu; iu = iu < 0 ? 0 : (iu > 2 ? 2 : iu);
        const float wu1 = fu - (float)iu;
        const float wu0 = 1.0f - wu1;

        float fv = (attr.y + 1.0f) * 1.5f;
        int iv = (int)fv; iv = iv < 0 ? 0 : (iv > 2 ? 2 : iv);
        const float wv1 = fv - (float)iv;
        const float wv0 = 1.0f - wv1;

        const int k0 = iu * 4 + iv;
        int   kb[4];
        float tw[4];
        kb[0] = k0;     tw[0] = wu0 * wv0;
        kb[1] = k0 + 1; tw[1] = wu0 * wv1;
        kb[2] = k0 + 4; tw[2] = wu1 * wv0;
        kb[3] = k0 + 5; tw[3] = wu1 * wv1;

        // gather x_j: 16 lanes of this edge read the same 64B -> L1 broadcast
        const float4* xv = (const float4*)(x + (size_t)col * 16);
        float xs[16];
#pragma unroll
        for (int q = 0; q < 4; ++q) {
            float4 t4 = xv[q];
            xs[4 * q + 0] = t4.x; xs[4 * q + 1] = t4.y;
            xs[4 * q + 2] = t4.z; xs[4 * q + 3] = t4.w;
        }

        float msg = 0.0f;
#pragma unroll
        for (int p = 0; p < 4; ++p) {
            const float t = tw[p];
            const float4* wp = (const float4*)&wl[f * FSLAB + kb[p] * 16];
#pragma unroll
            for (int i4 = 0; i4 < 4; ++i4) {
                const float4 w = wp[i4];
                msg += t * (xs[4 * i4 + 0] * w.x + xs[4 * i4 + 1] * w.y +
                            xs[4 * i4 + 2] * w.z + xs[4 * i4 + 3] * w.w);
            }
        }

        // one atomic per lane; a wave covers 4 rows x 16 consecutive floats
        unsafeAtomicAdd(out + (size_t)row * 16 + f, msg);
    }
}

extern "C" void kernel_launch(void* const* d_in, const int* in_sizes, int n_in,
                              void* d_out, int out_size, void* d_ws, size_t ws_size,
                              hipStream_t stream) {
    const float* x  = (const float*)d_in[0];
    const int*   ei = (const int*)d_in[1];
    const float* ea = (const float*)d_in[2];
    const float* w  = (const float*)d_in[3];
    float* out = (float*)d_out;

    const int n4 = out_size / 4;  // 400000 float4s
    zero_out_kernel<<<(n4 + 255) / 256, 256, 0, stream>>>((float4*)out, n4);

    const int blocks = N_EDGES / EDGES_PER_BLOCK;  // 6250
    basis_conv_edges<<<blocks, 256, 0, stream>>>(x, ei, ea, w, out);
}